// Round 1
// baseline (177.189 us; speedup 1.0000x reference)
//
#include <hip/hip_runtime.h>
#include <math.h>

#define NPOS 13824   // 24*24*24
#define CDIM 64
#define BTCH 2

// ---------------------------------------------------------------------------
// Kernel 1: Q/K/V/GX projections (1x1x1 convs) as tiled GEMM, output (B,N,C)
// layout so the attention kernel reads lane-coalesced (lane = channel).
// Also zeroes the pool accumulator in workspace.
// ---------------------------------------------------------------------------
__global__ __launch_bounds__(256) void qkvg_kernel(
    const float* __restrict__ x,
    const float* __restrict__ Wq, const float* __restrict__ bq,
    const float* __restrict__ Wk, const float* __restrict__ bk,
    const float* __restrict__ Wv, const float* __restrict__ bv,
    const float* __restrict__ Wg,
    float* __restrict__ Qb, float* __restrict__ Kb, float* __restrict__ Vb,
    float* __restrict__ GXb, float* __restrict__ pool)
{
  __shared__ __align__(16) float xs [64*64];
  __shared__ __align__(16) float wqt[64*64];
  __shared__ __align__(16) float wkt[64*64];
  __shared__ __align__(16) float wvt[64*64];
  __shared__ __align__(16) float wgt[64*64];
  const int t  = threadIdx.x;
  const int bi = blockIdx.x;
  const int b  = bi / 216;                  // 216 tiles of 64 positions per batch
  const int n0 = (bi - b*216) * 64;
  if (bi == 0 && t < 128) pool[t] = 0.0f;

  #pragma unroll
  for (int k = 0; k < 16; ++k) {
    int idx = t + k*256;                    // 0..4095
    int lo = idx & 63, hi = idx >> 6;       // transposed stage: [c_in][c_out]
    wqt[lo*64 + hi] = Wq[idx];
    wkt[lo*64 + hi] = Wk[idx];
    wvt[lo*64 + hi] = Wv[idx];
    wgt[lo*64 + hi] = Wg[hi*128 + lo];      // first 64 columns of Wg
    xs[idx] = x[(b*64 + hi)*NPOS + n0 + lo]; // xs[c][nn], coalesced load
  }
  __syncthreads();

  const int c0  = (t & 15) * 4;             // 4 output channels
  const int nn0 = (t >> 4) * 4;             // 4 positions
  float aq[4][4] = {}; float ak[4][4] = {}; float av[4][4] = {}; float ag[4][4] = {};
  #pragma unroll 4
  for (int cp = 0; cp < 64; ++cp) {
    const float4 xv4 = *(const float4*)&xs [cp*64 + nn0];
    const float4 q4  = *(const float4*)&wqt[cp*64 + c0];
    const float4 k4  = *(const float4*)&wkt[cp*64 + c0];
    const float4 v4  = *(const float4*)&wvt[cp*64 + c0];
    const float4 g4  = *(const float4*)&wgt[cp*64 + c0];
    const float xa[4] = {xv4.x, xv4.y, xv4.z, xv4.w};
    const float qa[4] = {q4.x, q4.y, q4.z, q4.w};
    const float ka[4] = {k4.x, k4.y, k4.z, k4.w};
    const float va[4] = {v4.x, v4.y, v4.z, v4.w};
    const float ga[4] = {g4.x, g4.y, g4.z, g4.w};
    #pragma unroll
    for (int ci = 0; ci < 4; ++ci)
      #pragma unroll
      for (int ni = 0; ni < 4; ++ni) {
        aq[ci][ni] = fmaf(qa[ci], xa[ni], aq[ci][ni]);
        ak[ci][ni] = fmaf(ka[ci], xa[ni], ak[ci][ni]);
        av[ci][ni] = fmaf(va[ci], xa[ni], av[ci][ni]);
        ag[ci][ni] = fmaf(ga[ci], xa[ni], ag[ci][ni]);
      }
  }
  const float4 bq4 = *(const float4*)&bq[c0];
  const float4 bk4 = *(const float4*)&bk[c0];
  const float4 bv4 = *(const float4*)&bv[c0];
  #pragma unroll
  for (int ni = 0; ni < 4; ++ni) {
    const int p = b*NPOS + n0 + nn0 + ni;   // (B,N,C) layout: [p*64 + c]
    float4 o;
    o = make_float4(aq[0][ni]+bq4.x, aq[1][ni]+bq4.y, aq[2][ni]+bq4.z, aq[3][ni]+bq4.w);
    *(float4*)&Qb[p*64 + c0] = o;
    o = make_float4(ak[0][ni]+bk4.x, ak[1][ni]+bk4.y, ak[2][ni]+bk4.z, ak[3][ni]+bk4.w);
    *(float4*)&Kb[p*64 + c0] = o;
    o = make_float4(av[0][ni]+bv4.x, av[1][ni]+bv4.y, av[2][ni]+bv4.z, av[3][ni]+bv4.w);
    *(float4*)&Vb[p*64 + c0] = o;
    o = make_float4(ag[0][ni], ag[1][ni], ag[2][ni], ag[3][ni]); // bias bg added in k2
    *(float4*)&GXb[p*64 + c0] = o;
  }
}

// ---------------------------------------------------------------------------
// Kernel 2: per-position scalar attention (5 mem + 27 neighbors), gate,
// final mix, output store, spatial-mean partial pooling.
// One wave per position, lane = channel. Neighbor math is wave-uniform.
// ---------------------------------------------------------------------------
__global__ __launch_bounds__(256) void attn_kernel(
    const float* __restrict__ x,
    const float* __restrict__ Qb, const float* __restrict__ Kb,
    const float* __restrict__ Vb, const float* __restrict__ GXb,
    const float* __restrict__ bk, const float* __restrict__ bv,
    const float* __restrict__ memk, const float* __restrict__ memv,
    const float* __restrict__ Wg, const float* __restrict__ bg,
    float* __restrict__ out, float* __restrict__ pool)
{
  __shared__ __align__(16) float wgt2[64*64];   // Wg[:,64:128] transposed: [j][c]
  __shared__ __align__(16) float xls[4*64];     // x column per wave-position
  __shared__ __align__(16) float als[4*64];     // att values, reused for final out
  __shared__ __align__(16) float pls[4*128];    // pool reduce
  const int t = threadIdx.x;

  #pragma unroll
  for (int k = 0; k < 16; ++k) {
    int idx = t + k*256;                  // 0..4095
    int c = idx >> 6, j = idx & 63;       // coalesced read of Wg row segment
    wgt2[j*64 + c] = Wg[c*128 + 64 + j];
  }

  const int c = t & 63;
  const int w = __builtin_amdgcn_readfirstlane(t >> 6);   // wave id, scalar
  const float bk_c = bk[c];
  const float bv_c = bv[c];
  const float bg_c = bg[c];
  float mk[5], mv[5];
  #pragma unroll
  for (int m = 0; m < 5; ++m) { mk[m] = memk[c*5 + m]; mv[m] = memv[c*5 + m]; }
  float acc0 = 0.0f, acc1 = 0.0f;         // per-batch pool accumulators
  __syncthreads();

  for (int g = blockIdx.x; g < (BTCH*NPOS)/4; g += gridDim.x) {
    const int p0 = g * 4;                 // 4 consecutive positions, same batch
    {   // cooperative x stage: 16B-contiguous global segments
      int cc = t >> 2, j = t & 3;
      int p = p0 + j;
      int bb = (p >= NPOS) ? 1 : 0;
      int nn = p - bb*NPOS;
      xls[j*64 + cc] = x[(bb*64 + cc)*NPOS + nn];
    }
    __syncthreads();

    const int pw = __builtin_amdgcn_readfirstlane(p0 + w);
    const int b  = (pw >= NPOS) ? 1 : 0;
    const int n  = pw - b*NPOS;
    const int h  = n / 576;
    const int r  = n - h*576;
    const int d  = r / 24;
    const int w3 = r - d*24;
    const int bN = b * NPOS;

    const float q  = Qb[pw*64 + c];
    const float qs = q * 0.125f;          // 1/sqrt(64)

    // ---- pass 1: logits + max (keys; OOB neighbor key == bk[c]) ----
    float lg[32];
    float maxv = -1e30f;
    #pragma unroll
    for (int m = 0; m < 5; ++m) {
      float l = qs * mk[m];
      lg[m] = l; maxv = fmaxf(maxv, l);
    }
    #pragma unroll
    for (int i = 0; i < 3; ++i)
      #pragma unroll
      for (int j = 0; j < 3; ++j)
        #pragma unroll
        for (int l = 0; l < 3; ++l) {
          int hh = h + i - 1, dd = d + j - 1, ww = w3 + l - 1;
          bool inb = ((unsigned)hh < 24u) && ((unsigned)dd < 24u) && ((unsigned)ww < 24u);
          float key = inb ? Kb[(bN + hh*576 + dd*24 + ww)*64 + c] : bk_c;
          float lv = qs * key;
          lg[5 + i*9 + j*3 + l] = lv;
          maxv = fmaxf(maxv, lv);
        }

    // ---- pass 2: exp-sum + weighted values (OOB value == bv[c]) ----
    float s = 0.0f, o = 0.0f;
    #pragma unroll
    for (int m = 0; m < 5; ++m) {
      float pf = __expf(lg[m] - maxv);
      s += pf; o = fmaf(pf, mv[m], o);
    }
    #pragma unroll
    for (int i = 0; i < 3; ++i)
      #pragma unroll
      for (int j = 0; j < 3; ++j)
        #pragma unroll
        for (int l = 0; l < 3; ++l) {
          int hh = h + i - 1, dd = d + j - 1, ww = w3 + l - 1;
          bool inb = ((unsigned)hh < 24u) && ((unsigned)dd < 24u) && ((unsigned)ww < 24u);
          float val = inb ? Vb[(bN + hh*576 + dd*24 + ww)*64 + c] : bv_c;
          float pf = __expf(lg[5 + i*9 + j*3 + l] - maxv);
          s += pf; o = fmaf(pf, val, o);
        }
    const float att = o / s;
    const float xv  = xls[w*64 + c];
    als[w*64 + c] = att;
    __syncthreads();

    // ---- gate: GX (x-half, precomputed) + Wg[:,64:]·att + bg ----
    float gacc = GXb[pw*64 + c] + bg_c;
    #pragma unroll
    for (int j4 = 0; j4 < 16; ++j4) {
      const float4 a4 = *(const float4*)&als[w*64 + j4*4];
      gacc = fmaf(wgt2[(j4*4+0)*64 + c], a4.x, gacc);
      gacc = fmaf(wgt2[(j4*4+1)*64 + c], a4.y, gacc);
      gacc = fmaf(wgt2[(j4*4+2)*64 + c], a4.z, gacc);
      gacc = fmaf(wgt2[(j4*4+3)*64 + c], a4.w, gacc);
    }
    const float gate = 1.0f / (1.0f + __expf(-gacc));
    const float fin  = gate * att + (1.0f - gate) * xv;

    if (b == 0) acc0 += fin; else acc1 += fin;  // wave-uniform branch

    als[w*64 + c] = fin;                  // reuse att buffer for output stage
    __syncthreads();
    {   // cooperative store back to (B,C,H,D,W): 16B-contiguous segments
      int cc = t >> 2, j = t & 3;
      int p = p0 + j;
      int bb = (p >= NPOS) ? 1 : 0;
      int nn = p - bb*NPOS;
      out[(bb*64 + cc)*NPOS + nn] = als[j*64 + cc];
    }
    __syncthreads();
  }

  // ---- pool reduce across the 4 waves, then one atomic per (b,c) ----
  pls[w*128 + c]      = acc0;
  pls[w*128 + 64 + c] = acc1;
  __syncthreads();
  if (t < 128) {
    float sres = pls[t] + pls[128 + t] + pls[256 + t] + pls[384 + t];
    atomicAdd(&pool[t], sres);
  }
}

// ---------------------------------------------------------------------------
// Kernel 3: GRU cell on the pooled mean. Single tiny block.
// ---------------------------------------------------------------------------
__global__ __launch_bounds__(384) void gru_kernel(
    const float* __restrict__ prev,
    const float* __restrict__ W_ih, const float* __restrict__ W_hh,
    const float* __restrict__ b_ih, const float* __restrict__ b_hh,
    const float* __restrict__ pool, float* __restrict__ outmem)
{
  __shared__ float mu[128];
  __shared__ float gi[384];
  __shared__ float gh[384];
  const int t = threadIdx.x;
  if (t < 128) mu[t] = pool[t] * (1.0f / (float)NPOS);
  __syncthreads();
  {
    int b = t / 192, j = t - b*192;       // j in [0,192)
    float sgi = b_ih[j], sgh = b_hh[j];
    #pragma unroll 8
    for (int cc = 0; cc < 64; ++cc) {
      sgi = fmaf(mu[b*64 + cc],   W_ih[j*64 + cc], sgi);
      sgh = fmaf(prev[b*64 + cc], W_hh[j*64 + cc], sgh);
    }
    gi[t] = sgi; gh[t] = sgh;
  }
  __syncthreads();
  if (t < 128) {
    int b = t >> 6, cc = t & 63;
    float ir = gi[b*192 + cc],       hr = gh[b*192 + cc];
    float iz = gi[b*192 + 64 + cc],  hz = gh[b*192 + 64 + cc];
    float ii = gi[b*192 + 128 + cc], hn = gh[b*192 + 128 + cc];
    float rr = 1.0f / (1.0f + __expf(-(ir + hr)));
    float zz = 1.0f / (1.0f + __expf(-(iz + hz)));
    float ng = tanhf(ii + rr * hn);
    outmem[t] = (1.0f - zz) * ng + zz * prev[t];
  }
}

// ---------------------------------------------------------------------------
extern "C" void kernel_launch(void* const* d_in, const int* in_sizes, int n_in,
                              void* d_out, int out_size, void* d_ws, size_t ws_size,
                              hipStream_t stream) {
  const float* x    = (const float*)d_in[0];
  const float* prev = (const float*)d_in[1];
  const float* Wq   = (const float*)d_in[2];
  const float* bq   = (const float*)d_in[3];
  const float* Wk   = (const float*)d_in[4];
  const float* bk   = (const float*)d_in[5];
  const float* Wv   = (const float*)d_in[6];
  const float* bv   = (const float*)d_in[7];
  const float* memk = (const float*)d_in[8];
  const float* memv = (const float*)d_in[9];
  const float* Wg   = (const float*)d_in[10];
  const float* bg   = (const float*)d_in[11];
  const float* W_ih = (const float*)d_in[12];
  const float* W_hh = (const float*)d_in[13];
  const float* b_ih = (const float*)d_in[14];
  const float* b_hh = (const float*)d_in[15];

  float* out    = (float*)d_out;                 // (B,C,H,D,W) = 1769472 floats
  float* outmem = out + BTCH*CDIM*NPOS;          // (B,C)       = 128 floats

  const size_t SZ = (size_t)BTCH*NPOS*CDIM;      // 1769472
  float* wsf  = (float*)d_ws;
  float* Qb   = wsf;
  float* Kb   = wsf + SZ;
  float* Vb   = wsf + 2*SZ;
  float* GXb  = wsf + 3*SZ;
  float* pool = wsf + 4*SZ;                      // 128 floats

  qkvg_kernel<<<BTCH*216, 256, 0, stream>>>(x, Wq, bq, Wk, bk, Wv, bv, Wg,
                                            Qb, Kb, Vb, GXb, pool);
  attn_kernel<<<864, 256, 0, stream>>>(x, Qb, Kb, Vb, GXb, bk, bv, memk, memv,
                                       Wg, bg, out, pool);
  gru_kernel<<<1, 384, 0, stream>>>(prev, W_ih, W_hh, b_ih, b_hh, pool, outmem);
}

// Round 2
// 162.127 us; speedup vs baseline: 1.0929x; 1.0929x over previous
//
#include <hip/hip_runtime.h>
#include <math.h>

#define NPOS 13824   // 24*24*24
#define CDIM 64
#define BTCH 2
#define LOG2E 1.4426950408889634f

// ---------------------------------------------------------------------------
// Kernel 1: Q/K/V/GX projections (1x1x1 convs), output (B,N,C) layout, plus
// an x-transpose XT (N,C) emitted from registers. Zeroes pool.
// Weights staged transposed with stride-68 padding: conflict-free b128 reads.
// ---------------------------------------------------------------------------
__global__ __launch_bounds__(256) void qkvg_kernel(
    const float* __restrict__ x,
    const float* __restrict__ Wq, const float* __restrict__ bq,
    const float* __restrict__ Wk, const float* __restrict__ bk,
    const float* __restrict__ Wv, const float* __restrict__ bv,
    const float* __restrict__ Wg,
    float* __restrict__ Qb, float* __restrict__ Kb, float* __restrict__ Vb,
    float* __restrict__ GXb, float* __restrict__ XT, float* __restrict__ pool)
{
  // stride 68: 272 B = 17*16 -> float4-aligned rows; writes only 8-way conflicted
  __shared__ __align__(16) float wqt[64*68];
  __shared__ __align__(16) float wkt[64*68];
  __shared__ __align__(16) float wvt[64*68];
  __shared__ __align__(16) float wgt[64*68];
  const int t  = threadIdx.x;
  const int bi = blockIdx.x;
  const int b  = bi / 216;
  const int n0 = (bi - b*216) * 64;
  if (bi == 0 && t < 128) pool[t] = 0.0f;

  #pragma unroll
  for (int k = 0; k < 16; ++k) {
    int idx = t + k*256;                 // 0..4095
    int lo = idx & 63, hi = idx >> 6;    // lo = c_in col within row hi = c_out
    wqt[lo*68 + hi] = Wq[idx];           // [c_in][c_out]
    wkt[lo*68 + hi] = Wk[idx];
    wvt[lo*68 + hi] = Wv[idx];
    wgt[lo*68 + hi] = Wg[hi*128 + lo];   // first 64 columns of Wg
  }
  __syncthreads();

  const int c0  = (t & 15) * 4;          // 4 output channels
  const int nn0 = (t >> 4) * 4;          // 4 positions
  const float* xbase = x + (size_t)(b*64)*NPOS + n0 + nn0;
  float aq[4][4] = {}; float ak[4][4] = {}; float av[4][4] = {}; float ag[4][4] = {};
  #pragma unroll 4
  for (int cp = 0; cp < 64; ++cp) {
    const float4 xv4 = *(const float4*)(xbase + (size_t)cp*NPOS);   // L1-resident
    const float4 q4  = *(const float4*)&wqt[cp*68 + c0];
    const float4 k4  = *(const float4*)&wkt[cp*68 + c0];
    const float4 v4  = *(const float4*)&wvt[cp*68 + c0];
    const float4 g4  = *(const float4*)&wgt[cp*68 + c0];
    const float xa[4] = {xv4.x, xv4.y, xv4.z, xv4.w};
    const float qa[4] = {q4.x, q4.y, q4.z, q4.w};
    const float ka[4] = {k4.x, k4.y, k4.z, k4.w};
    const float va[4] = {v4.x, v4.y, v4.z, v4.w};
    const float ga[4] = {g4.x, g4.y, g4.z, g4.w};
    #pragma unroll
    for (int ci = 0; ci < 4; ++ci)
      #pragma unroll
      for (int ni = 0; ni < 4; ++ni) {
        aq[ci][ni] = fmaf(qa[ci], xa[ni], aq[ci][ni]);
        ak[ci][ni] = fmaf(ka[ci], xa[ni], ak[ci][ni]);
        av[ci][ni] = fmaf(va[ci], xa[ni], av[ci][ni]);
        ag[ci][ni] = fmaf(ga[ci], xa[ni], ag[ci][ni]);
      }
  }
  const float4 bq4 = *(const float4*)&bq[c0];
  const float4 bk4 = *(const float4*)&bk[c0];
  const float4 bv4 = *(const float4*)&bv[c0];
  #pragma unroll
  for (int ni = 0; ni < 4; ++ni) {
    const int p = b*NPOS + n0 + nn0 + ni;   // (N,C) layout: [p*64 + c]
    float4 o;
    o = make_float4(aq[0][ni]+bq4.x, aq[1][ni]+bq4.y, aq[2][ni]+bq4.z, aq[3][ni]+bq4.w);
    *(float4*)&Qb[p*64 + c0] = o;
    o = make_float4(ak[0][ni]+bk4.x, ak[1][ni]+bk4.y, ak[2][ni]+bk4.z, ak[3][ni]+bk4.w);
    *(float4*)&Kb[p*64 + c0] = o;
    o = make_float4(av[0][ni]+bv4.x, av[1][ni]+bv4.y, av[2][ni]+bv4.z, av[3][ni]+bv4.w);
    *(float4*)&Vb[p*64 + c0] = o;
    o = make_float4(ag[0][ni], ag[1][ni], ag[2][ni], ag[3][ni]); // bg added in attn
    *(float4*)&GXb[p*64 + c0] = o;
  }
  // XT: re-read this block's x tile (L1-hot) rows c0..c0+3 and emit transposed
  float4 xr[4];
  #pragma unroll
  for (int e = 0; e < 4; ++e)
    xr[e] = *(const float4*)(x + (size_t)(b*64 + c0 + e)*NPOS + n0 + nn0);
  const float xre[4][4] = {{xr[0].x,xr[0].y,xr[0].z,xr[0].w},
                           {xr[1].x,xr[1].y,xr[1].z,xr[1].w},
                           {xr[2].x,xr[2].y,xr[2].z,xr[2].w},
                           {xr[3].x,xr[3].y,xr[3].z,xr[3].w}};
  #pragma unroll
  for (int ni = 0; ni < 4; ++ni) {
    const int p = b*NPOS + n0 + nn0 + ni;
    *(float4*)&XT[p*64 + c0] = make_float4(xre[0][ni], xre[1][ni], xre[2][ni], xre[3][ni]);
  }
}

// ---------------------------------------------------------------------------
// Kernel 2: tiled attention. One block per 3x3x3 position tile; 5x5x5 K/V
// halo staged in LDS (union with the Wg2 stage). Gate weights in registers.
// No __syncthreads in the compute loop. Writes (N,C) result into QOT (aliases
// the Q buffer — each slot is read-then-written by the same lane).
// ---------------------------------------------------------------------------
__global__ __launch_bounds__(256) void attn_kernel(
    float* __restrict__ QOT,            // in: Q (N,C); out: fin (N,C)
    const float* __restrict__ Kb, const float* __restrict__ Vb,
    const float* __restrict__ GXb, const float* __restrict__ XT,
    const float* __restrict__ bk, const float* __restrict__ bv,
    const float* __restrict__ memk, const float* __restrict__ memv,
    const float* __restrict__ Wg, const float* __restrict__ bg)
{
  __shared__ __align__(16) float smem[16000];  // Ks[0,8000) Vs[8000,16000); wgt2 overlay [0,4160)
  __shared__ __align__(16) float als[256];
  const int t = threadIdx.x;
  const int c = t & 63;
  const int w = t >> 6;

  // stage Wg[:,64:] into padded-65 transpose (coalesced global, conflict-free LDS)
  #pragma unroll
  for (int k = 0; k < 16; ++k) {
    int u = t + k*256;                   // 0..4095
    int cp = u >> 6, j = u & 63;
    smem[j*65 + cp] = Wg[cp*128 + 64 + j];
  }
  __syncthreads();
  float wg2reg[64];
  #pragma unroll
  for (int j = 0; j < 64; ++j) wg2reg[j] = smem[j*65 + c];  // lane c: Wg[c][64+j]
  float mk[5], mv[5];
  #pragma unroll
  for (int m = 0; m < 5; ++m) { mk[m] = memk[c*5 + m]; mv[m] = memv[c*5 + m]; }
  const float bg_c = bg[c];
  __syncthreads();                        // wgt2 fully consumed into registers

  // tile decode: 512 tiles (8x8x8) per batch
  const int bi = blockIdx.x;
  const int b  = bi >> 9;
  const int tb = bi & 511;
  const int h0 = (tb >> 6) * 3;
  const int d0 = ((tb >> 3) & 7) * 3;
  const int w0 = (tb & 7) * 3;
  const int bN = b * NPOS;

  // stage 5x5x5 K/V halo (OOB -> bias)
  for (int u = t; u < 125*16; u += 256) {
    int pos = u >> 4, q4 = u & 15;
    int ph = pos / 25, pr = pos - ph*25;
    int pd = pr / 5,  pw = pr - pd*5;
    int hh = h0 - 1 + ph, dd = d0 - 1 + pd, ww = w0 - 1 + pw;
    bool inb = ((unsigned)hh < 24u) && ((unsigned)dd < 24u) && ((unsigned)ww < 24u);
    float4 kf, vf;
    if (inb) {
      const size_t off = ((size_t)(bN + hh*576 + dd*24 + ww))*64 + q4*4;
      kf = *(const float4*)(Kb + off);
      vf = *(const float4*)(Vb + off);
    } else {
      kf = ((const float4*)bk)[q4];
      vf = ((const float4*)bv)[q4];
    }
    *(float4*)&smem[pos*64 + q4*4]        = kf;
    *(float4*)&smem[8000 + pos*64 + q4*4] = vf;
  }
  __syncthreads();

  for (int li = w; li < 27; li += 4) {
    const int lh = li / 9, lr = li - lh*9;
    const int ld = lr / 3, lw = lr - ld*3;
    const int p  = bN + (h0+lh)*576 + (d0+ld)*24 + (w0+lw);
    const int hb = (lh*25 + ld*5 + lw)*64 + c;        // halo corner index

    const float q2 = QOT[p*64 + c] * (0.125f * LOG2E); // logits in base-2 domain
    float lg[32];
    #pragma unroll
    for (int m = 0; m < 5; ++m) lg[m] = q2 * mk[m];
    #pragma unroll
    for (int i = 0; i < 3; ++i)
      #pragma unroll
      for (int j = 0; j < 3; ++j)
        #pragma unroll
        for (int l = 0; l < 3; ++l)
          lg[5 + i*9 + j*3 + l] = q2 * smem[hb + (i*25 + j*5 + l)*64];

    float m0 = lg[0], m1 = lg[1], m2 = lg[2], m3 = lg[3];
    #pragma unroll
    for (int s4 = 4; s4 < 32; s4 += 4) {
      m0 = fmaxf(m0, lg[s4]);   m1 = fmaxf(m1, lg[s4+1]);
      m2 = fmaxf(m2, lg[s4+2]); m3 = fmaxf(m3, lg[s4+3]);
    }
    const float maxv = fmaxf(fmaxf(m0, m1), fmaxf(m2, m3));

    float s0 = 0.f, s1 = 0.f, o0 = 0.f, o1 = 0.f;
    #pragma unroll
    for (int m = 0; m < 5; ++m) {
      float pf = exp2f(lg[m] - maxv);
      if (m & 1) { s1 += pf; o1 = fmaf(pf, mv[m], o1); }
      else       { s0 += pf; o0 = fmaf(pf, mv[m], o0); }
    }
    #pragma unroll
    for (int i = 0; i < 3; ++i)
      #pragma unroll
      for (int j = 0; j < 3; ++j)
        #pragma unroll
        for (int l = 0; l < 3; ++l) {
          int s4 = i*9 + j*3 + l;
          float val = smem[8000 + hb + (i*25 + j*5 + l)*64];
          float pf = exp2f(lg[5 + s4] - maxv);
          if (s4 & 1) { s1 += pf; o1 = fmaf(pf, val, o1); }
          else        { s0 += pf; o0 = fmaf(pf, val, o0); }
        }
    const float att = (o0 + o1) * __builtin_amdgcn_rcpf(s0 + s1);

    als[w*64 + c] = att;                      // wave-local, ordered by lgkmcnt
    float g0 = GXb[p*64 + c] + bg_c, g1 = 0.f, g2 = 0.f, g3 = 0.f;
    #pragma unroll
    for (int j4 = 0; j4 < 16; ++j4) {
      const float4 a4 = *(const float4*)&als[w*64 + j4*4];  // broadcast reads
      g0 = fmaf(wg2reg[j4*4+0], a4.x, g0);
      g1 = fmaf(wg2reg[j4*4+1], a4.y, g1);
      g2 = fmaf(wg2reg[j4*4+2], a4.z, g2);
      g3 = fmaf(wg2reg[j4*4+3], a4.w, g3);
    }
    const float gl   = (g0 + g1) + (g2 + g3);
    const float gate = __builtin_amdgcn_rcpf(1.0f + exp2f(-LOG2E * gl));
    const float xv   = XT[p*64 + c];
    QOT[p*64 + c] = fmaf(gate, att - xv, xv); // gate*att + (1-gate)*x
  }
}

// ---------------------------------------------------------------------------
// Kernel 3: (N,C) -> (B,C,N) transpose through padded LDS + fused pool sum.
// ---------------------------------------------------------------------------
__global__ __launch_bounds__(256) void outpool_kernel(
    const float* __restrict__ OT, float* __restrict__ out, float* __restrict__ pool)
{
  __shared__ __align__(16) float ls[64*65];
  const int t  = threadIdx.x;
  const int bi = blockIdx.x;
  const int b  = bi / 216;
  const int n0 = (bi - b*216) * 64;
  #pragma unroll
  for (int i = 0; i < 16; ++i) {
    int u = i*256 + t;
    int pos = u >> 6, cc = u & 63;
    ls[cc*65 + pos] = OT[(size_t)(b*NPOS + n0 + pos)*64 + cc];  // coalesced read
  }
  __syncthreads();
  #pragma unroll
  for (int i = 0; i < 16; ++i) {
    int u = i*256 + t;
    int cc = u >> 6, j = u & 63;
    out[(size_t)(b*64 + cc)*NPOS + n0 + j] = ls[cc*65 + j];     // coalesced write
  }
  if (t < 64) {
    float s = 0.0f;
    #pragma unroll 8
    for (int j = 0; j < 64; ++j) s += ls[t*65 + j];
    atomicAdd(&pool[b*64 + t], s);
  }
}

// ---------------------------------------------------------------------------
// Kernel 4: GRU cell on the pooled mean. Single tiny block, float4 loads.
// ---------------------------------------------------------------------------
__global__ __launch_bounds__(384) void gru_kernel(
    const float* __restrict__ prev,
    const float* __restrict__ W_ih, const float* __restrict__ W_hh,
    const float* __restrict__ b_ih, const float* __restrict__ b_hh,
    const float* __restrict__ pool, float* __restrict__ outmem)
{
  __shared__ __align__(16) float mu[128];
  __shared__ float gi[384];
  __shared__ float gh[384];
  const int t = threadIdx.x;
  if (t < 128) mu[t] = pool[t] * (1.0f / (float)NPOS);
  __syncthreads();
  {
    int b = t / 192, j = t - b*192;
    const float4* wi4 = (const float4*)(W_ih + (size_t)j*64);
    const float4* wh4 = (const float4*)(W_hh + (size_t)j*64);
    const float4* mu4 = (const float4*)(mu + b*64);
    const float4* pv4 = (const float4*)(prev + b*64);
    float sgi = b_ih[j], sgh = b_hh[j];
    #pragma unroll
    for (int k = 0; k < 16; ++k) {
      float4 wv = wi4[k], m4 = mu4[k];
      sgi = fmaf(wv.x, m4.x, sgi); sgi = fmaf(wv.y, m4.y, sgi);
      sgi = fmaf(wv.z, m4.z, sgi); sgi = fmaf(wv.w, m4.w, sgi);
      float4 hv = wh4[k], p4 = pv4[k];
      sgh = fmaf(hv.x, p4.x, sgh); sgh = fmaf(hv.y, p4.y, sgh);
      sgh = fmaf(hv.z, p4.z, sgh); sgh = fmaf(hv.w, p4.w, sgh);
    }
    gi[t] = sgi; gh[t] = sgh;
  }
  __syncthreads();
  if (t < 128) {
    int b = t >> 6, cc = t & 63;
    float ir = gi[b*192 + cc],       hr = gh[b*192 + cc];
    float iz = gi[b*192 + 64 + cc],  hz = gh[b*192 + 64 + cc];
    float ii = gi[b*192 + 128 + cc], hn = gh[b*192 + 128 + cc];
    float rr = 1.0f / (1.0f + __expf(-(ir + hr)));
    float zz = 1.0f / (1.0f + __expf(-(iz + hz)));
    float ng = tanhf(ii + rr * hn);
    outmem[t] = (1.0f - zz) * ng + zz * prev[t];
  }
}

// ---------------------------------------------------------------------------
extern "C" void kernel_launch(void* const* d_in, const int* in_sizes, int n_in,
                              void* d_out, int out_size, void* d_ws, size_t ws_size,
                              hipStream_t stream) {
  const float* x    = (const float*)d_in[0];
  const float* prev = (const float*)d_in[1];
  const float* Wq   = (const float*)d_in[2];
  const float* bq   = (const float*)d_in[3];
  const float* Wk   = (const float*)d_in[4];
  const float* bk   = (const float*)d_in[5];
  const float* Wv   = (const float*)d_in[6];
  const float* bv   = (const float*)d_in[7];
  const float* memk = (const float*)d_in[8];
  const float* memv = (const float*)d_in[9];
  const float* Wg   = (const float*)d_in[10];
  const float* bg   = (const float*)d_in[11];
  const float* W_ih = (const float*)d_in[12];
  const float* W_hh = (const float*)d_in[13];
  const float* b_ih = (const float*)d_in[14];
  const float* b_hh = (const float*)d_in[15];

  float* out    = (float*)d_out;                 // (B,C,H,D,W) = 1769472 floats
  float* outmem = out + (size_t)BTCH*CDIM*NPOS;  // (B,C) = 128 floats

  const size_t SZ = (size_t)BTCH*NPOS*CDIM;      // 1769472
  float* wsf  = (float*)d_ws;
  float* Qb   = wsf;                             // also attn output (OT)
  float* Kb   = wsf + SZ;
  float* Vb   = wsf + 2*SZ;
  float* GXb  = wsf + 3*SZ;
  float* pool = wsf + 4*SZ;                      // 128 floats
  float* XT   = out;                             // x transpose, consumed before
                                                 // outpool overwrites d_out

  qkvg_kernel<<<BTCH*216, 256, 0, stream>>>(x, Wq, bq, Wk, bk, Wv, bv, Wg,
                                            Qb, Kb, Vb, GXb, XT, pool);
  attn_kernel<<<BTCH*512, 256, 0, stream>>>(Qb, Kb, Vb, GXb, XT,
                                            bk, bv, memk, memv, Wg, bg);
  outpool_kernel<<<BTCH*216, 256, 0, stream>>>(Qb, out, pool);
  gru_kernel<<<1, 384, 0, stream>>>(prev, W_ih, W_hh, b_ih, b_hh, pool, outmem);
}